// Round 2
// baseline (195.127 us; speedup 1.0000x reference)
//
#include <hip/hip_runtime.h>
#include <hip/hip_bf16.h>
#include <stdint.h>

#define NB 8
#define DIMG 2048
#define HWN 196
#define PN 1568
#define PPAD 1600
#define DMID 1024
#define NC 80
#define DWORD 300

typedef short bf16x8 __attribute__((ext_vector_type(8)));
typedef float f32x4 __attribute__((ext_vector_type(4)));

__device__ __forceinline__ unsigned short f2bf(float x) {
  union { float f; unsigned u; } c; c.f = x;
  unsigned r = c.u + 0x7FFFu + ((c.u >> 16) & 1u);
  return (unsigned short)(r >> 16);
}

// ---------------------------------------------------------------- transpose
// img [B][2048][196] -> fmap f32 [1568][2048] and fmapH bf16 [1600][2048]
__global__ void k_transpose(const float* __restrict__ img, float* __restrict__ fmap,
                            unsigned short* __restrict__ fmapH) {
  __shared__ float tile[32][33];
  int d0 = blockIdx.x * 32, h0 = blockIdx.y * 32, b = blockIdx.z;
  int tx = threadIdx.x, ty = threadIdx.y;
  const float* src = img + (size_t)b * DIMG * HWN;
#pragma unroll
  for (int i = 0; i < 32; i += 8) {
    int hw = h0 + tx;
    tile[ty + i][tx] = (hw < HWN) ? src[(size_t)(d0 + ty + i) * HWN + hw] : 0.f;
  }
  __syncthreads();
#pragma unroll
  for (int i = 0; i < 32; i += 8) {
    int hw = h0 + ty + i;
    if (hw < HWN) {
      float v = tile[tx][ty + i];
      size_t o = (size_t)(b * HWN + hw) * DIMG + d0 + tx;
      fmap[o] = v;
      fmapH[o] = f2bf(v);
    }
  }
}

// ---------------------------------------------------------------- prep (merged):
//  bx in [0,2048)      : W1 -> bf16
//  bx in [2048,2128)   : f_wd [80][1024] = word @ W2^T, prescaled by 2*log2(e)
//  bx in [2128,2192)   : partial[16][1024] n-chunked  Wa @ W3
__global__ __launch_bounds__(256) void k_prep(const float* __restrict__ W1,
                                              unsigned short* __restrict__ W1h,
                                              const float* __restrict__ word,
                                              const float* __restrict__ W2,
                                              float* __restrict__ fwd,
                                              const float* __restrict__ Wa,
                                              const float* __restrict__ W3,
                                              float* __restrict__ partial) {
  __shared__ float sm[DWORD];
  int bx = blockIdx.x, t = threadIdx.x;
  if (bx < 2048) {
    int i = (bx * 256 + t) * 4;
    f32x4 v = *(const f32x4*)(W1 + i);
    ushort4 s;
    s.x = f2bf(v[0]); s.y = f2bf(v[1]); s.z = f2bf(v[2]); s.w = f2bf(v[3]);
    *(ushort4*)(W1h + i) = s;
  } else if (bx < 2128) {
    int c = bx - 2048;
    for (int i = t; i < DWORD; i += 256) sm[i] = word[(size_t)c * DWORD + i];
    __syncthreads();
    const float SC = 2.8853900817779268f;  // 2*log2(e)
#pragma unroll
    for (int j = 0; j < 4; ++j) {
      int m = t + j * 256;
      const f32x4* w2r = (const f32x4*)(W2 + (size_t)m * DWORD);
      f32x4 av = {0.f, 0.f, 0.f, 0.f};
      for (int k = 0; k < DWORD / 4; ++k) {
        f32x4 wv = *(const f32x4*)&sm[k * 4];
        f32x4 rv = w2r[k];
#pragma unroll
        for (int u = 0; u < 4; ++u) av[u] = fmaf(wv[u], rv[u], av[u]);
      }
      fwd[(size_t)c * DMID + m] = (av[0] + av[1] + av[2] + av[3]) * SC;
    }
  } else {
    int idx = bx - 2128;
    int m = (idx & 3) * 256 + t;
    int n0 = (idx >> 2) * 64;
    float acc = 0.f;
    for (int n = n0; n < n0 + 64; ++n) acc = fmaf(Wa[n], W3[(size_t)n * DMID + m], acc);
    partial[(size_t)(idx >> 2) * DMID + m] = acc;
  }
}

// ---------------------------------------------------------------- GEMM: fwh[1600][1024] = fmapH[1600][2048] x W1h[1024][2048]^T  (bf16 MFMA)
#define GLDS(g, l) \
  __builtin_amdgcn_global_load_lds((const __attribute__((address_space(1))) void*)(g), \
                                   (__attribute__((address_space(3))) void*)(l), 16, 0, 0)

__global__ __launch_bounds__(256) void k_gemm(const unsigned short* __restrict__ A,
                                              const unsigned short* __restrict__ Bw,
                                              float* __restrict__ C) {
  __shared__ __align__(16) unsigned short As[64 * 32];
  __shared__ __align__(16) unsigned short Bs[64 * 32];
  int m0 = blockIdx.x * 64;   // 25 blocks (rows padded to 1600)
  int n0 = blockIdx.y * 64;   // 16 blocks
  int t = threadIdx.x;
  int w = t >> 6, l = t & 63;
  int wr = w >> 1, wc = w & 1;
  f32x4 zero = {0.f, 0.f, 0.f, 0.f};
  f32x4 acc00 = zero, acc01 = zero, acc10 = zero, acc11 = zero;

  int sr = t >> 2, sk = (t & 3) << 3;  // staging: 16B per thread, LDS-linear
  const unsigned short* ga = A + (size_t)(m0 + sr) * 2048 + sk;
  const unsigned short* gb = Bw + (size_t)(n0 + sr) * 2048 + sk;
  unsigned short* la = &As[sr * 32 + sk];
  unsigned short* lb = &Bs[sr * 32 + sk];

  int row_a = wr * 32 + (l & 15);
  int row_b = wc * 32 + (l & 15);
  int ko = (l >> 4) << 3;

  for (int kk = 0; kk < 2048; kk += 32) {
    __syncthreads();
    GLDS(ga + kk, la);
    GLDS(gb + kk, lb);
    __syncthreads();
    bf16x8 a0 = *(const bf16x8*)&As[row_a * 32 + ko];
    bf16x8 a1 = *(const bf16x8*)&As[(row_a + 16) * 32 + ko];
    bf16x8 b0 = *(const bf16x8*)&Bs[row_b * 32 + ko];
    bf16x8 b1 = *(const bf16x8*)&Bs[(row_b + 16) * 32 + ko];
    acc00 = __builtin_amdgcn_mfma_f32_16x16x32_bf16(a0, b0, acc00, 0, 0, 0);
    acc01 = __builtin_amdgcn_mfma_f32_16x16x32_bf16(a0, b1, acc01, 0, 0, 0);
    acc10 = __builtin_amdgcn_mfma_f32_16x16x32_bf16(a1, b0, acc10, 0, 0, 0);
    acc11 = __builtin_amdgcn_mfma_f32_16x16x32_bf16(a1, b1, acc11, 0, 0, 0);
  }
  int cr = (l >> 4) << 2, cc = l & 15;
#pragma unroll
  for (int q = 0; q < 4; ++q) {
    C[(size_t)(m0 + wr * 32 + cr + q) * DMID + n0 + wc * 32 + cc] = acc00[q];
    C[(size_t)(m0 + wr * 32 + cr + q) * DMID + n0 + wc * 32 + 16 + cc] = acc01[q];
    C[(size_t)(m0 + wr * 32 + 16 + cr + q) * DMID + n0 + wc * 32 + cc] = acc10[q];
    C[(size_t)(m0 + wr * 32 + 16 + cr + q) * DMID + n0 + wc * 32 + 16 + cc] = acc11[q];
  }
}

// ---------------------------------------------------------------- coef logits [1568][80]
// wl[m] = -2 * sum_s partial[s][m]  (reduced on the fly, L2-resident)
#define MC 128
__global__ __launch_bounds__(256) void k_coef(const float* __restrict__ fwh,
                                              const float* __restrict__ fwd,
                                              const float* __restrict__ partial,
                                              float* __restrict__ coef) {
  __shared__ __align__(16) float al[16][132];
  __shared__ __align__(16) float bl[16][132];
  __shared__ __align__(16) float wl[MC];
  int p0 = blockIdx.x * 16, c0 = blockIdx.y * 16;
  int t = threadIdx.x;
  int pi = t >> 4, ci = t & 15;
  int sr = t >> 4, sc8 = (t & 15) << 3;
  float acc = 0.f;
  for (int mc = 0; mc < DMID; mc += MC) {
    __syncthreads();
    {
      const f32x4* sa = (const f32x4*)(fwh + (size_t)(p0 + sr) * DMID + mc + sc8);
      f32x4 v0 = sa[0], v1 = sa[1];
      *(f32x4*)&al[sr][sc8] = v0;
      *(f32x4*)&al[sr][sc8 + 4] = v1;
      const f32x4* sb = (const f32x4*)(fwd + (size_t)(c0 + sr) * DMID + mc + sc8);
      f32x4 u0 = sb[0], u1 = sb[1];
      *(f32x4*)&bl[sr][sc8] = u0;
      *(f32x4*)&bl[sr][sc8 + 4] = u1;
      if (t < MC / 4) {
        f32x4 v = {0.f, 0.f, 0.f, 0.f};
#pragma unroll
        for (int s = 0; s < 16; ++s) {
          f32x4 p = *(const f32x4*)(partial + (size_t)s * DMID + mc + t * 4);
#pragma unroll
          for (int u = 0; u < 4; ++u) v[u] += p[u];
        }
#pragma unroll
        for (int u = 0; u < 4; ++u) v[u] *= -2.f;
        *(f32x4*)&wl[t * 4] = v;
      }
    }
    __syncthreads();
    for (int mm = 0; mm < MC; mm += 4) {
      f32x4 av = *(const f32x4*)&al[pi][mm];
      f32x4 bv = *(const f32x4*)&bl[ci][mm];
      f32x4 wv = *(const f32x4*)&wl[mm];
#pragma unroll
      for (int u = 0; u < 4; ++u) {
        float arg = av[u] * bv[u];                       // = 2*log2e * x
        float e = __builtin_amdgcn_exp2f(arg);           // 2^(2 log2e x) = e^(2x)
        float r = __builtin_amdgcn_rcpf(1.f + e);        // 1/(1+e^(2x))
        acc = fmaf(wv[u], r, acc);                       // += (-2 w_eff) * r
      }
    }
  }
  coef[(size_t)(p0 + pi) * NC + c0 + ci] = acc;
}

// ---------------------------------------------------------------- softmax over 196 positions per (b,c), in-place
__global__ void k_softmax(float* __restrict__ coef) {
  int bc = blockIdx.x;
  int b = bc / NC, c = bc % NC;
  int l = threadIdx.x;  // 64
  float v[4];
  float mx = -1e30f;
#pragma unroll
  for (int i = 0; i < 4; ++i) {
    int hw = l + i * 64;
    v[i] = (hw < HWN) ? coef[(size_t)(b * HWN + hw) * NC + c] : -1e30f;
    mx = fmaxf(mx, v[i]);
  }
#pragma unroll
  for (int s = 32; s; s >>= 1) mx = fmaxf(mx, __shfl_xor(mx, s, 64));
  float sum = 0.f;
#pragma unroll
  for (int i = 0; i < 4; ++i) {
    int hw = l + i * 64;
    v[i] = __builtin_amdgcn_exp2f((v[i] - mx) * 1.4426950408889634f);
    if (hw < HWN) sum += v[i];
  }
#pragma unroll
  for (int s = 32; s; s >>= 1) sum += __shfl_xor(sum, s, 64);
  float inv = 1.f / sum;
#pragma unroll
  for (int i = 0; i < 4; ++i) {
    int hw = l + i * 64;
    if (hw < HWN) coef[(size_t)(b * HWN + hw) * NC + c] = v[i] * inv;
  }
}

// ---------------------------------------------------------------- pooling: out[b][c][d] = sum_hw coef[b,hw,c] * fmap[b,hw,d]
__global__ __launch_bounds__(256) void k_pool(const float* __restrict__ coef,
                                              const float* __restrict__ fmap,
                                              float* __restrict__ out) {
  __shared__ __align__(16) float wt[HWN][16];
  int dc = blockIdx.x * 256, cg = blockIdx.y * 16, b = blockIdx.z;
  int t = threadIdx.x;
  for (int i = t; i < HWN * 16; i += 256) {
    int hw = i >> 4, j = i & 15;
    wt[hw][j] = coef[(size_t)(b * HWN + hw) * NC + cg + j];
  }
  __syncthreads();
  float acc[16];
#pragma unroll
  for (int j = 0; j < 16; ++j) acc[j] = 0.f;
  const float* fp = fmap + (size_t)b * HWN * DIMG + dc + t;
  for (int hw = 0; hw < HWN; ++hw) {
    float v = fp[(size_t)hw * DIMG];
#pragma unroll
    for (int j = 0; j < 16; ++j) acc[j] = fmaf(wt[hw][j], v, acc[j]);
  }
#pragma unroll
  for (int j = 0; j < 16; ++j)
    out[((size_t)b * NC + cg + j) * DIMG + dc + t] = acc[j];
}

// ----------------------------------------------------------------
extern "C" void kernel_launch(void* const* d_in, const int* in_sizes, int n_in,
                              void* d_out, int out_size, void* d_ws, size_t ws_size,
                              hipStream_t stream) {
  const float* img  = (const float*)d_in[1];
  const float* word = (const float*)d_in[2];
  const float* W1   = (const float*)d_in[3];
  const float* W2   = (const float*)d_in[4];
  const float* W3   = (const float*)d_in[5];
  const float* Wa   = (const float*)d_in[7];
  // b3 (d_in[6]) and ba (d_in[8]) are softmax-shift-invariant -> dropped.
  float* out = (float*)d_out;
  char* ws = (char*)d_ws;

  float*          fmap    = (float*)(ws + 0);                  // 1568*2048*4 = 12,845,056
  unsigned short* fmapH   = (unsigned short*)(ws + 12845056);  // 1600*2048*2 =  6,553,600
  unsigned short* W1h     = (unsigned short*)(ws + 19398656);  // 1024*2048*2 =  4,194,304
  float*          fwh     = (float*)(ws + 23592960);           // 1600*1024*4 =  6,553,600
  float*          fwd     = (float*)(ws + 30146560);           //   80*1024*4 =    327,680
  float*          partial = (float*)(ws + 30474240);           // 16*1024*4   =     65,536
  float*          coef    = (float*)(ws + 30539776);           // 1568*80*4   =    501,760

  hipLaunchKernelGGL(k_transpose, dim3(64, 7, 8), dim3(32, 8), 0, stream, img, fmap, fmapH);
  hipLaunchKernelGGL(k_prep, dim3(2192), dim3(256), 0, stream,
                     W1, W1h, word, W2, fwd, Wa, W3, partial);
  hipLaunchKernelGGL(k_gemm, dim3(25, 16), dim3(256), 0, stream, fmapH, W1h, fwh);
  hipLaunchKernelGGL(k_coef, dim3(98, 5), dim3(256), 0, stream, fwh, fwd, partial, coef);
  hipLaunchKernelGGL(k_softmax, dim3(640), dim3(64), 0, stream, coef);
  hipLaunchKernelGGL(k_pool, dim3(8, 5, 8), dim3(256), 0, stream, coef, fmap, out);
  (void)in_sizes; (void)n_in; (void)out_size; (void)ws_size;
}

// Round 3
// 125.231 us; speedup vs baseline: 1.5581x; 1.5581x over previous
//
#include <hip/hip_runtime.h>
#include <hip/hip_bf16.h>
#include <stdint.h>

#define NB 8
#define DIMG 2048
#define HWN 196
#define PN 1568
#define PPAD 1600
#define DMID 1024
#define NC 80
#define DWORD 300

typedef short bf16x8 __attribute__((ext_vector_type(8)));
typedef float f32x4 __attribute__((ext_vector_type(4)));

__device__ __forceinline__ unsigned short f2bf(float x) {
  union { float f; unsigned u; } c; c.f = x;
  unsigned r = c.u + 0x7FFFu + ((c.u >> 16) & 1u);
  return (unsigned short)(r >> 16);
}

// ---------------------------------------------------------------- transpose
// img [B][2048][196] -> fmap f32 [1568][2048] and fmapH bf16 [1600][2048]
__global__ void k_transpose(const float* __restrict__ img, float* __restrict__ fmap,
                            unsigned short* __restrict__ fmapH) {
  __shared__ float tile[32][33];
  int d0 = blockIdx.x * 32, h0 = blockIdx.y * 32, b = blockIdx.z;
  int tx = threadIdx.x, ty = threadIdx.y;
  const float* src = img + (size_t)b * DIMG * HWN;
#pragma unroll
  for (int i = 0; i < 32; i += 8) {
    int hw = h0 + tx;
    tile[ty + i][tx] = (hw < HWN) ? src[(size_t)(d0 + ty + i) * HWN + hw] : 0.f;
  }
  __syncthreads();
#pragma unroll
  for (int i = 0; i < 32; i += 8) {
    int hw = h0 + ty + i;
    if (hw < HWN) {
      float v = tile[tx][ty + i];
      size_t o = (size_t)(b * HWN + hw) * DIMG + d0 + tx;
      fmap[o] = v;
      fmapH[o] = f2bf(v);
    }
  }
}

// ---------------------------------------------------------------- W1 -> bf16 (no LDS, full occupancy)
__global__ void k_cvt(const float* __restrict__ w1, unsigned short* __restrict__ w1h) {
  int i = (blockIdx.x * 256 + threadIdx.x) * 4;
  f32x4 v = *(const f32x4*)(w1 + i);
  ushort4 s;
  s.x = f2bf(v[0]); s.y = f2bf(v[1]); s.z = f2bf(v[2]); s.w = f2bf(v[3]);
  *(ushort4*)(w1h + i) = s;
}

// ---------------------------------------------------------------- fwd + weff (coalesced, LDS-staged)
//  bx in [0,80)  : fwd[c][m] = SC * sum_k word[c][k]*W2[m][k]; tile = 16 c x 64 m
//  bx in [80,144): partial[s][m] = sum_{n in chunk s} Wa[n]*W3[n][m]
__global__ __launch_bounds__(256) void k_fwdweff(const float* __restrict__ word,
                                                 const float* __restrict__ W2,
                                                 float* __restrict__ fwd,
                                                 const float* __restrict__ Wa,
                                                 const float* __restrict__ W3,
                                                 float* __restrict__ partial) {
  __shared__ __align__(16) float w2s[64 * DWORD];   // 76.8 KB
  __shared__ __align__(16) float wds[16 * DWORD];   // 19.2 KB
  int bx = blockIdx.x, t = threadIdx.x;
  if (bx < 80) {
    int m0 = (bx & 15) * 64, c0 = (bx >> 4) * 16;
    const float SC = 2.8853900817779268f;  // 2*log2(e)
    for (int u = t; u < 64 * 75; u += 256) {
      int r = u / 75, q = u - r * 75;
      *(f32x4*)&w2s[r * DWORD + q * 4] =
          *(const f32x4*)(W2 + (size_t)(m0 + r) * DWORD + q * 4);
    }
    for (int u = t; u < 16 * 75; u += 256) {
      int r = u / 75, q = u - r * 75;
      f32x4 v = *(const f32x4*)(word + (size_t)(c0 + r) * DWORD + q * 4);
      *(f32x4*)&wds[r * DWORD + q * 4] = v * SC;
    }
    __syncthreads();
    int ci = t >> 4, mi = t & 15;
    f32x4 a0 = {0.f, 0.f, 0.f, 0.f}, a1 = a0, a2 = a0, a3 = a0;
    const float* wr = &wds[ci * DWORD];
    for (int q = 0; q < 75; ++q) {
      f32x4 wv = *(const f32x4*)&wr[q * 4];
      f32x4 b0 = *(const f32x4*)&w2s[(mi)*DWORD + q * 4];
      f32x4 b1 = *(const f32x4*)&w2s[(mi + 16) * DWORD + q * 4];
      f32x4 b2 = *(const f32x4*)&w2s[(mi + 32) * DWORD + q * 4];
      f32x4 b3 = *(const f32x4*)&w2s[(mi + 48) * DWORD + q * 4];
#pragma unroll
      for (int u = 0; u < 4; ++u) {
        a0[u] = fmaf(wv[u], b0[u], a0[u]);
        a1[u] = fmaf(wv[u], b1[u], a1[u]);
        a2[u] = fmaf(wv[u], b2[u], a2[u]);
        a3[u] = fmaf(wv[u], b3[u], a3[u]);
      }
    }
    float* dst = fwd + (size_t)(c0 + ci) * DMID + m0 + mi;
    dst[0]  = a0[0] + a0[1] + a0[2] + a0[3];
    dst[16] = a1[0] + a1[1] + a1[2] + a1[3];
    dst[32] = a2[0] + a2[1] + a2[2] + a2[3];
    dst[48] = a3[0] + a3[1] + a3[2] + a3[3];
  } else {
    int idx = bx - 80;
    int m = (idx & 3) * 256 + t;
    int n0 = (idx >> 2) * 64;
    float acc = 0.f;
    for (int n = n0; n < n0 + 64; ++n) acc = fmaf(Wa[n], W3[(size_t)n * DMID + m], acc);
    partial[(size_t)(idx >> 2) * DMID + m] = acc;
  }
}

// ---------------------------------------------------------------- GEMM: fwh[1600][1024] = fmapH[1600][2048] x W1h[1024][2048]^T  (bf16 MFMA)
#define GLDS(g, l) \
  __builtin_amdgcn_global_load_lds((const __attribute__((address_space(1))) void*)(g), \
                                   (__attribute__((address_space(3))) void*)(l), 16, 0, 0)

__global__ __launch_bounds__(256) void k_gemm(const unsigned short* __restrict__ A,
                                              const unsigned short* __restrict__ Bw,
                                              float* __restrict__ C) {
  __shared__ __align__(16) unsigned short As[64 * 32];
  __shared__ __align__(16) unsigned short Bs[64 * 32];
  int m0 = blockIdx.x * 64;   // 25 blocks (rows padded to 1600)
  int n0 = blockIdx.y * 64;   // 16 blocks
  int t = threadIdx.x;
  int w = t >> 6, l = t & 63;
  int wr = w >> 1, wc = w & 1;
  f32x4 zero = {0.f, 0.f, 0.f, 0.f};
  f32x4 acc00 = zero, acc01 = zero, acc10 = zero, acc11 = zero;

  int sr = t >> 2, sk = (t & 3) << 3;  // staging: 16B per thread, LDS-linear
  const unsigned short* ga = A + (size_t)(m0 + sr) * 2048 + sk;
  const unsigned short* gb = Bw + (size_t)(n0 + sr) * 2048 + sk;
  unsigned short* la = &As[sr * 32 + sk];
  unsigned short* lb = &Bs[sr * 32 + sk];

  int row_a = wr * 32 + (l & 15);
  int row_b = wc * 32 + (l & 15);
  int ko = (l >> 4) << 3;

  for (int kk = 0; kk < 2048; kk += 32) {
    __syncthreads();
    GLDS(ga + kk, la);
    GLDS(gb + kk, lb);
    __syncthreads();
    bf16x8 a0 = *(const bf16x8*)&As[row_a * 32 + ko];
    bf16x8 a1 = *(const bf16x8*)&As[(row_a + 16) * 32 + ko];
    bf16x8 b0 = *(const bf16x8*)&Bs[row_b * 32 + ko];
    bf16x8 b1 = *(const bf16x8*)&Bs[(row_b + 16) * 32 + ko];
    acc00 = __builtin_amdgcn_mfma_f32_16x16x32_bf16(a0, b0, acc00, 0, 0, 0);
    acc01 = __builtin_amdgcn_mfma_f32_16x16x32_bf16(a0, b1, acc01, 0, 0, 0);
    acc10 = __builtin_amdgcn_mfma_f32_16x16x32_bf16(a1, b0, acc10, 0, 0, 0);
    acc11 = __builtin_amdgcn_mfma_f32_16x16x32_bf16(a1, b1, acc11, 0, 0, 0);
  }
  int cr = (l >> 4) << 2, cc = l & 15;
#pragma unroll
  for (int q = 0; q < 4; ++q) {
    C[(size_t)(m0 + wr * 32 + cr + q) * DMID + n0 + wc * 32 + cc] = acc00[q];
    C[(size_t)(m0 + wr * 32 + cr + q) * DMID + n0 + wc * 32 + 16 + cc] = acc01[q];
    C[(size_t)(m0 + wr * 32 + 16 + cr + q) * DMID + n0 + wc * 32 + cc] = acc10[q];
    C[(size_t)(m0 + wr * 32 + 16 + cr + q) * DMID + n0 + wc * 32 + 16 + cc] = acc11[q];
  }
}

// ---------------------------------------------------------------- coef logits [1568][80]
// wl[m] = -2 * sum_s partial[s][m]  (reduced on the fly, L2-resident)
#define MC 128
__global__ __launch_bounds__(256) void k_coef(const float* __restrict__ fwh,
                                              const float* __restrict__ fwd,
                                              const float* __restrict__ partial,
                                              float* __restrict__ coef) {
  __shared__ __align__(16) float al[16][132];
  __shared__ __align__(16) float bl[16][132];
  __shared__ __align__(16) float wl[MC];
  int p0 = blockIdx.x * 16, c0 = blockIdx.y * 16;
  int t = threadIdx.x;
  int pi = t >> 4, ci = t & 15;
  int sr = t >> 4, sc8 = (t & 15) << 3;
  float acc = 0.f;
  for (int mc = 0; mc < DMID; mc += MC) {
    __syncthreads();
    {
      const f32x4* sa = (const f32x4*)(fwh + (size_t)(p0 + sr) * DMID + mc + sc8);
      f32x4 v0 = sa[0], v1 = sa[1];
      *(f32x4*)&al[sr][sc8] = v0;
      *(f32x4*)&al[sr][sc8 + 4] = v1;
      const f32x4* sb = (const f32x4*)(fwd + (size_t)(c0 + sr) * DMID + mc + sc8);
      f32x4 u0 = sb[0], u1 = sb[1];
      *(f32x4*)&bl[sr][sc8] = u0;
      *(f32x4*)&bl[sr][sc8 + 4] = u1;
      if (t < MC / 4) {
        f32x4 v = {0.f, 0.f, 0.f, 0.f};
#pragma unroll
        for (int s = 0; s < 16; ++s) {
          f32x4 p = *(const f32x4*)(partial + (size_t)s * DMID + mc + t * 4);
#pragma unroll
          for (int u = 0; u < 4; ++u) v[u] += p[u];
        }
#pragma unroll
        for (int u = 0; u < 4; ++u) v[u] *= -2.f;
        *(f32x4*)&wl[t * 4] = v;
      }
    }
    __syncthreads();
    for (int mm = 0; mm < MC; mm += 4) {
      f32x4 av = *(const f32x4*)&al[pi][mm];
      f32x4 bv = *(const f32x4*)&bl[ci][mm];
      f32x4 wv = *(const f32x4*)&wl[mm];
#pragma unroll
      for (int u = 0; u < 4; ++u) {
        float arg = av[u] * bv[u];                       // = 2*log2e * x
        float e = __builtin_amdgcn_exp2f(arg);           // 2^(2 log2e x) = e^(2x)
        float r = __builtin_amdgcn_rcpf(1.f + e);        // 1/(1+e^(2x))
        acc = fmaf(wv[u], r, acc);                       // += (-2 w_eff) * r
      }
    }
  }
  coef[(size_t)(p0 + pi) * NC + c0 + ci] = acc;
}

// ---------------------------------------------------------------- softmax over 196 positions per (b,c), in-place
__global__ void k_softmax(float* __restrict__ coef) {
  int bc = blockIdx.x;
  int b = bc / NC, c = bc % NC;
  int l = threadIdx.x;  // 64
  float v[4];
  float mx = -1e30f;
#pragma unroll
  for (int i = 0; i < 4; ++i) {
    int hw = l + i * 64;
    v[i] = (hw < HWN) ? coef[(size_t)(b * HWN + hw) * NC + c] : -1e30f;
    mx = fmaxf(mx, v[i]);
  }
#pragma unroll
  for (int s = 32; s; s >>= 1) mx = fmaxf(mx, __shfl_xor(mx, s, 64));
  float sum = 0.f;
#pragma unroll
  for (int i = 0; i < 4; ++i) {
    int hw = l + i * 64;
    v[i] = __builtin_amdgcn_exp2f((v[i] - mx) * 1.4426950408889634f);
    if (hw < HWN) sum += v[i];
  }
#pragma unroll
  for (int s = 32; s; s >>= 1) sum += __shfl_xor(sum, s, 64);
  float inv = 1.f / sum;
#pragma unroll
  for (int i = 0; i < 4; ++i) {
    int hw = l + i * 64;
    if (hw < HWN) coef[(size_t)(b * HWN + hw) * NC + c] = v[i] * inv;
  }
}

// ---------------------------------------------------------------- pooling: out[b][c][d] = sum_hw coef[b,hw,c] * fmap[b,hw,d]
__global__ __launch_bounds__(256) void k_pool(const float* __restrict__ coef,
                                              const float* __restrict__ fmap,
                                              float* __restrict__ out) {
  __shared__ __align__(16) float wt[HWN][16];
  int dc = blockIdx.x * 256, cg = blockIdx.y * 16, b = blockIdx.z;
  int t = threadIdx.x;
  for (int i = t; i < HWN * 16; i += 256) {
    int hw = i >> 4, j = i & 15;
    wt[hw][j] = coef[(size_t)(b * HWN + hw) * NC + cg + j];
  }
  __syncthreads();
  float acc[16];
#pragma unroll
  for (int j = 0; j < 16; ++j) acc[j] = 0.f;
  const float* fp = fmap + (size_t)b * HWN * DIMG + dc + t;
  for (int hw = 0; hw < HWN; ++hw) {
    float v = fp[(size_t)hw * DIMG];
#pragma unroll
    for (int j = 0; j < 16; ++j) acc[j] = fmaf(wt[hw][j], v, acc[j]);
  }
#pragma unroll
  for (int j = 0; j < 16; ++j)
    out[((size_t)b * NC + cg + j) * DIMG + dc + t] = acc[j];
}

// ----------------------------------------------------------------
extern "C" void kernel_launch(void* const* d_in, const int* in_sizes, int n_in,
                              void* d_out, int out_size, void* d_ws, size_t ws_size,
                              hipStream_t stream) {
  const float* img  = (const float*)d_in[1];
  const float* word = (const float*)d_in[2];
  const float* W1   = (const float*)d_in[3];
  const float* W2   = (const float*)d_in[4];
  const float* W3   = (const float*)d_in[5];
  const float* Wa   = (const float*)d_in[7];
  // b3 (d_in[6]) and ba (d_in[8]) are softmax-shift-invariant -> dropped.
  float* out = (float*)d_out;
  char* ws = (char*)d_ws;

  float*          fmap    = (float*)(ws + 0);                  // 1568*2048*4 = 12,845,056
  unsigned short* fmapH   = (unsigned short*)(ws + 12845056);  // 1600*2048*2 =  6,553,600
  unsigned short* W1h     = (unsigned short*)(ws + 19398656);  // 1024*2048*2 =  4,194,304
  float*          fwh     = (float*)(ws + 23592960);           // 1600*1024*4 =  6,553,600
  float*          fwd     = (float*)(ws + 30146560);           //   80*1024*4 =    327,680
  float*          partial = (float*)(ws + 30474240);           // 16*1024*4   =     65,536
  float*          coef    = (float*)(ws + 30539776);           // 1568*80*4   =    501,760

  hipLaunchKernelGGL(k_transpose, dim3(64, 7, 8), dim3(32, 8), 0, stream, img, fmap, fmapH);
  hipLaunchKernelGGL(k_cvt, dim3(2048), dim3(256), 0, stream, W1, W1h);
  hipLaunchKernelGGL(k_fwdweff, dim3(144), dim3(256), 0, stream,
                     word, W2, fwd, Wa, W3, partial);
  hipLaunchKernelGGL(k_gemm, dim3(25, 16), dim3(256), 0, stream, fmapH, W1h, fwh);
  hipLaunchKernelGGL(k_coef, dim3(98, 5), dim3(256), 0, stream, fwh, fwd, partial, coef);
  hipLaunchKernelGGL(k_softmax, dim3(640), dim3(64), 0, stream, coef);
  hipLaunchKernelGGL(k_pool, dim3(8, 5, 8), dim3(256), 0, stream, coef, fmap, out);
  (void)in_sizes; (void)n_in; (void)out_size; (void)ws_size;
}

// Round 4
// 118.324 us; speedup vs baseline: 1.6491x; 1.0584x over previous
//
#include <hip/hip_runtime.h>
#include <hip/hip_bf16.h>
#include <stdint.h>

#define NB 8
#define DIMG 2048
#define HWN 196
#define PN 1568
#define PPAD 1600
#define DMID 1024
#define NC 80
#define DWORD 300

typedef short bf16x8 __attribute__((ext_vector_type(8)));
typedef float f32x4 __attribute__((ext_vector_type(4)));

__device__ __forceinline__ unsigned short f2bf(float x) {
  union { float f; unsigned u; } c; c.f = x;
  unsigned r = c.u + 0x7FFFu + ((c.u >> 16) & 1u);
  return (unsigned short)(r >> 16);
}

// ---------------------------------------------------------------- transpose + W1 cvt (merged)
// bx < 3584 : img [B][2048][196] -> fmap f32 [1568][2048] + fmapH bf16 [1600][2048]
// bx >= 3584: W1 f32 -> bf16
__global__ void k_tc(const float* __restrict__ img, float* __restrict__ fmap,
                     unsigned short* __restrict__ fmapH,
                     const float* __restrict__ W1, unsigned short* __restrict__ W1h) {
  __shared__ float tile[32][33];
  int bx = blockIdx.x;
  int tx = threadIdx.x, ty = threadIdx.y;
  if (bx < 3584) {
    int d0 = (bx & 63) * 32;
    int rem = bx >> 6;
    int h0 = (rem % 7) * 32, b = rem / 7;
    const float* src = img + (size_t)b * DIMG * HWN;
#pragma unroll
    for (int i = 0; i < 32; i += 8) {
      int hw = h0 + tx;
      tile[ty + i][tx] = (hw < HWN) ? src[(size_t)(d0 + ty + i) * HWN + hw] : 0.f;
    }
    __syncthreads();
#pragma unroll
    for (int i = 0; i < 32; i += 8) {
      int hw = h0 + ty + i;
      if (hw < HWN) {
        float v = tile[tx][ty + i];
        size_t o = (size_t)(b * HWN + hw) * DIMG + d0 + tx;
        fmap[o] = v;
        fmapH[o] = f2bf(v);
      }
    }
  } else {
    int tid = ty * 32 + tx;
    int i = ((bx - 3584) * 256 + tid) * 4;
    f32x4 v = *(const f32x4*)(W1 + i);
    ushort4 s;
    s.x = f2bf(v[0]); s.y = f2bf(v[1]); s.z = f2bf(v[2]); s.w = f2bf(v[3]);
    *(ushort4*)(W1h + i) = s;
  }
}

// ---------------------------------------------------------------- fwd + weff (coalesced, LDS-staged)
__global__ __launch_bounds__(256) void k_fwdweff(const float* __restrict__ word,
                                                 const float* __restrict__ W2,
                                                 float* __restrict__ fwd,
                                                 const float* __restrict__ Wa,
                                                 const float* __restrict__ W3,
                                                 float* __restrict__ partial) {
  __shared__ __align__(16) float w2s[64 * DWORD];   // 76.8 KB
  __shared__ __align__(16) float wds[16 * DWORD];   // 19.2 KB
  int bx = blockIdx.x, t = threadIdx.x;
  if (bx < 80) {
    int m0 = (bx & 15) * 64, c0 = (bx >> 4) * 16;
    const float SC = 2.8853900817779268f;  // 2*log2(e)
    for (int u = t; u < 64 * 75; u += 256) {
      int r = u / 75, q = u - r * 75;
      *(f32x4*)&w2s[r * DWORD + q * 4] =
          *(const f32x4*)(W2 + (size_t)(m0 + r) * DWORD + q * 4);
    }
    for (int u = t; u < 16 * 75; u += 256) {
      int r = u / 75, q = u - r * 75;
      f32x4 v = *(const f32x4*)(word + (size_t)(c0 + r) * DWORD + q * 4);
      *(f32x4*)&wds[r * DWORD + q * 4] = v * SC;
    }
    __syncthreads();
    int ci = t >> 4, mi = t & 15;
    f32x4 a0 = {0.f, 0.f, 0.f, 0.f}, a1 = a0, a2 = a0, a3 = a0;
    const float* wr = &wds[ci * DWORD];
    for (int q = 0; q < 75; ++q) {
      f32x4 wv = *(const f32x4*)&wr[q * 4];
      f32x4 b0 = *(const f32x4*)&w2s[(mi)*DWORD + q * 4];
      f32x4 b1 = *(const f32x4*)&w2s[(mi + 16) * DWORD + q * 4];
      f32x4 b2 = *(const f32x4*)&w2s[(mi + 32) * DWORD + q * 4];
      f32x4 b3 = *(const f32x4*)&w2s[(mi + 48) * DWORD + q * 4];
#pragma unroll
      for (int u = 0; u < 4; ++u) {
        a0[u] = fmaf(wv[u], b0[u], a0[u]);
        a1[u] = fmaf(wv[u], b1[u], a1[u]);
        a2[u] = fmaf(wv[u], b2[u], a2[u]);
        a3[u] = fmaf(wv[u], b3[u], a3[u]);
      }
    }
    float* dst = fwd + (size_t)(c0 + ci) * DMID + m0 + mi;
    dst[0]  = a0[0] + a0[1] + a0[2] + a0[3];
    dst[16] = a1[0] + a1[1] + a1[2] + a1[3];
    dst[32] = a2[0] + a2[1] + a2[2] + a2[3];
    dst[48] = a3[0] + a3[1] + a3[2] + a3[3];
  } else {
    int idx = bx - 80;
    int m = (idx & 3) * 256 + t;
    int n0 = (idx >> 2) * 64;
    float acc = 0.f;
    for (int n = n0; n < n0 + 64; ++n) acc = fmaf(Wa[n], W3[(size_t)n * DMID + m], acc);
    partial[(size_t)(idx >> 2) * DMID + m] = acc;
  }
}

// ---------------------------------------------------------------- GEMM: fwh[1600][1024] = fmapH x W1h^T
// BK=64, triple-buffered 2-deep prefetch, counted vmcnt, XOR chunk-swizzled LDS.
#define GLDS(g, l) \
  __builtin_amdgcn_global_load_lds((const __attribute__((address_space(1))) void*)(g), \
                                   (__attribute__((address_space(3))) void*)(l), 16, 0, 0)

__global__ __launch_bounds__(256) void k_gemm(const unsigned short* __restrict__ A,
                                              const unsigned short* __restrict__ Bw,
                                              float* __restrict__ C) {
  __shared__ __align__(16) unsigned short As[3][64 * 64];
  __shared__ __align__(16) unsigned short Bs[3][64 * 64];
  int m0 = blockIdx.x * 64, n0 = blockIdx.y * 64;
  int t = threadIdx.x;
  int w = t >> 6, l = t & 63;
  int wr = w >> 1, wc = w & 1;
  f32x4 zero = {0.f, 0.f, 0.f, 0.f};
  f32x4 acc00 = zero, acc01 = zero, acc10 = zero, acc11 = zero;

  // staging: 512 16B-chunks per tile; thread t handles chunks t and t+256.
  // LDS slot (row, c) receives global chunk (c ^ (row&7))  [involution]
  int r0 = t >> 3, c0 = t & 7;
  int r1 = r0 + 32;
  const unsigned short* ga0 = A + (size_t)(m0 + r0) * 2048 + ((c0 ^ (r0 & 7)) << 3);
  const unsigned short* ga1 = A + (size_t)(m0 + r1) * 2048 + ((c0 ^ (r1 & 7)) << 3);
  const unsigned short* gb0 = Bw + (size_t)(n0 + r0) * 2048 + ((c0 ^ (r0 & 7)) << 3);
  const unsigned short* gb1 = Bw + (size_t)(n0 + r1) * 2048 + ((c0 ^ (r1 & 7)) << 3);

  // frag read element-offsets (row*64 + (cc ^ (row&7))*8); (row+16)&7 == row&7
  int ra = wr * 32 + (l & 15);
  int rb = wc * 32 + (l & 15);
  int cc = l >> 4;  // 0..3
  int a_k0 = ra * 64 + (((cc) ^ (ra & 7)) << 3);
  int a_k1 = ra * 64 + (((cc + 4) ^ (ra & 7)) << 3);
  int b_k0 = rb * 64 + (((cc) ^ (rb & 7)) << 3);
  int b_k1 = rb * 64 + (((cc + 4) ^ (rb & 7)) << 3);

#define STAGE(bi, kk) do { \
    GLDS(ga0 + (kk), &As[bi][t * 8]); \
    GLDS(ga1 + (kk), &As[bi][t * 8 + 2048]); \
    GLDS(gb0 + (kk), &Bs[bi][t * 8]); \
    GLDS(gb1 + (kk), &Bs[bi][t * 8 + 2048]); \
  } while (0)

#define COMPUTE(bi) do { \
    const unsigned short* ap = As[bi]; \
    const unsigned short* bp = Bs[bi]; \
    bf16x8 A0 = *(const bf16x8*)(ap + a_k0); \
    bf16x8 A1 = *(const bf16x8*)(ap + a_k0 + 1024); \
    bf16x8 B0 = *(const bf16x8*)(bp + b_k0); \
    bf16x8 B1 = *(const bf16x8*)(bp + b_k0 + 1024); \
    acc00 = __builtin_amdgcn_mfma_f32_16x16x32_bf16(A0, B0, acc00, 0, 0, 0); \
    acc01 = __builtin_amdgcn_mfma_f32_16x16x32_bf16(A0, B1, acc01, 0, 0, 0); \
    acc10 = __builtin_amdgcn_mfma_f32_16x16x32_bf16(A1, B0, acc10, 0, 0, 0); \
    acc11 = __builtin_amdgcn_mfma_f32_16x16x32_bf16(A1, B1, acc11, 0, 0, 0); \
    bf16x8 A2 = *(const bf16x8*)(ap + a_k1); \
    bf16x8 A3 = *(const bf16x8*)(ap + a_k1 + 1024); \
    bf16x8 B2 = *(const bf16x8*)(bp + b_k1); \
    bf16x8 B3 = *(const bf16x8*)(bp + b_k1 + 1024); \
    acc00 = __builtin_amdgcn_mfma_f32_16x16x32_bf16(A2, B2, acc00, 0, 0, 0); \
    acc01 = __builtin_amdgcn_mfma_f32_16x16x32_bf16(A2, B3, acc01, 0, 0, 0); \
    acc10 = __builtin_amdgcn_mfma_f32_16x16x32_bf16(A3, B2, acc10, 0, 0, 0); \
    acc11 = __builtin_amdgcn_mfma_f32_16x16x32_bf16(A3, B3, acc11, 0, 0, 0); \
  } while (0)

  STAGE(0, 0);
  STAGE(1, 64);
  asm volatile("s_waitcnt vmcnt(4)" ::: "memory");
  __builtin_amdgcn_s_barrier();
  __builtin_amdgcn_sched_barrier(0);
  for (int kt = 0; kt < 32; ++kt) {
    int cur = kt % 3;
    if (kt < 30) STAGE((kt + 2) % 3, (kt + 2) * 64);
    COMPUTE(cur);
    if (kt < 30) {
      asm volatile("s_waitcnt vmcnt(4)" ::: "memory");
      __builtin_amdgcn_s_barrier();
      __builtin_amdgcn_sched_barrier(0);
    } else if (kt == 30) {
      asm volatile("s_waitcnt vmcnt(0)" ::: "memory");
      __builtin_amdgcn_s_barrier();
      __builtin_amdgcn_sched_barrier(0);
    }
  }
  int cr = (l >> 4) << 2, ccn = l & 15;
#pragma unroll
  for (int q = 0; q < 4; ++q) {
    C[(size_t)(m0 + wr * 32 + cr + q) * DMID + n0 + wc * 32 + ccn] = acc00[q];
    C[(size_t)(m0 + wr * 32 + cr + q) * DMID + n0 + wc * 32 + 16 + ccn] = acc01[q];
    C[(size_t)(m0 + wr * 32 + 16 + cr + q) * DMID + n0 + wc * 32 + ccn] = acc10[q];
    C[(size_t)(m0 + wr * 32 + 16 + cr + q) * DMID + n0 + wc * 32 + 16 + ccn] = acc11[q];
  }
#undef STAGE
#undef COMPUTE
}

// ---------------------------------------------------------------- coef logits [1568][80] (raw, pre-softmax)
#define MC 128
__global__ __launch_bounds__(256) void k_coef(const float* __restrict__ fwh,
                                              const float* __restrict__ fwd,
                                              const float* __restrict__ partial,
                                              float* __restrict__ coef) {
  __shared__ __align__(16) float al[16][132];
  __shared__ __align__(16) float bl[16][132];
  __shared__ __align__(16) float wl[MC];
  int p0 = blockIdx.x * 16, c0 = blockIdx.y * 16;
  int t = threadIdx.x;
  int pi = t >> 4, ci = t & 15;
  int sr = t >> 4, sc8 = (t & 15) << 3;
  float acc = 0.f;
  for (int mc = 0; mc < DMID; mc += MC) {
    __syncthreads();
    {
      const f32x4* sa = (const f32x4*)(fwh + (size_t)(p0 + sr) * DMID + mc + sc8);
      f32x4 v0 = sa[0], v1 = sa[1];
      *(f32x4*)&al[sr][sc8] = v0;
      *(f32x4*)&al[sr][sc8 + 4] = v1;
      const f32x4* sb = (const f32x4*)(fwd + (size_t)(c0 + sr) * DMID + mc + sc8);
      f32x4 u0 = sb[0], u1 = sb[1];
      *(f32x4*)&bl[sr][sc8] = u0;
      *(f32x4*)&bl[sr][sc8 + 4] = u1;
      if (t < MC / 4) {
        f32x4 v = {0.f, 0.f, 0.f, 0.f};
#pragma unroll
        for (int s = 0; s < 16; ++s) {
          f32x4 p = *(const f32x4*)(partial + (size_t)s * DMID + mc + t * 4);
#pragma unroll
          for (int u = 0; u < 4; ++u) v[u] += p[u];
        }
#pragma unroll
        for (int u = 0; u < 4; ++u) v[u] *= -2.f;
        *(f32x4*)&wl[t * 4] = v;
      }
    }
    __syncthreads();
    for (int mm = 0; mm < MC; mm += 4) {
      f32x4 av = *(const f32x4*)&al[pi][mm];
      f32x4 bv = *(const f32x4*)&bl[ci][mm];
      f32x4 wv = *(const f32x4*)&wl[mm];
#pragma unroll
      for (int u = 0; u < 4; ++u) {
        float arg = av[u] * bv[u];                       // = 2*log2e * x
        float e = __builtin_amdgcn_exp2f(arg);           // e^(2x)
        float r = __builtin_amdgcn_rcpf(1.f + e);        // 1/(1+e^(2x))
        acc = fmaf(wv[u], r, acc);                       // += (-2 w_eff) * r
      }
    }
  }
  coef[(size_t)(p0 + pi) * NC + c0 + ci] = acc;
}

// ---------------------------------------------------------------- softmax + pooling (merged)
// out[b][c][d] = sum_hw softmax_hw(coef)[b,hw,c] * fmap[b,hw,d]
__global__ __launch_bounds__(256) void k_pool(const float* __restrict__ coef,
                                              const float* __restrict__ fmap,
                                              float* __restrict__ out) {
  __shared__ __align__(16) float wt[HWN][16];
  __shared__ float red[16][16];
  __shared__ float mxs[16], inv[16];
  int dc = blockIdx.x * 256, cg = blockIdx.y * 16, b = blockIdx.z;
  int t = threadIdx.x;
  for (int i = t; i < HWN * 16; i += 256) {
    int hw = i >> 4, j = i & 15;
    wt[hw][j] = coef[(size_t)(b * HWN + hw) * NC + cg + j];
  }
  __syncthreads();
  int j = t & 15, g = t >> 4;
  float pm = -1e30f;
  for (int hw = g; hw < HWN; hw += 16) pm = fmaxf(pm, wt[hw][j]);
  red[g][j] = pm;
  __syncthreads();
  if (t < 16) {
    float m = red[0][t];
#pragma unroll
    for (int g2 = 1; g2 < 16; ++g2) m = fmaxf(m, red[g2][t]);
    mxs[t] = m;
  }
  __syncthreads();
  float mj = mxs[j], ps = 0.f;
  for (int hw = g; hw < HWN; hw += 16) {
    float e = __builtin_amdgcn_exp2f((wt[hw][j] - mj) * 1.4426950408889634f);
    wt[hw][j] = e;
    ps += e;
  }
  red[g][j] = ps;
  __syncthreads();
  if (t < 16) {
    float s = 0.f;
#pragma unroll
    for (int g2 = 0; g2 < 16; ++g2) s += red[g2][t];
    inv[t] = 1.f / s;
  }
  __syncthreads();
  float acc[16];
#pragma unroll
  for (int q = 0; q < 16; ++q) acc[q] = 0.f;
  const float* fp = fmap + (size_t)b * HWN * DIMG + dc + t;
  for (int hw = 0; hw < HWN; ++hw) {
    float v = fp[(size_t)hw * DIMG];
#pragma unroll
    for (int q = 0; q < 16; ++q) acc[q] = fmaf(wt[hw][q], v, acc[q]);
  }
#pragma unroll
  for (int q = 0; q < 16; ++q)
    out[((size_t)b * NC + cg + q) * DIMG + dc + t] = acc[q] * inv[q];
}

// ----------------------------------------------------------------
extern "C" void kernel_launch(void* const* d_in, const int* in_sizes, int n_in,
                              void* d_out, int out_size, void* d_ws, size_t ws_size,
                              hipStream_t stream) {
  const float* img  = (const float*)d_in[1];
  const float* word = (const float*)d_in[2];
  const float* W1   = (const float*)d_in[3];
  const float* W2   = (const float*)d_in[4];
  const float* W3   = (const float*)d_in[5];
  const float* Wa   = (const float*)d_in[7];
  // b3 (d_in[6]) and ba (d_in[8]) are softmax-shift-invariant -> dropped.
  float* out = (float*)d_out;
  char* ws = (char*)d_ws;

  float*          fmap    = (float*)(ws + 0);                  // 12,845,056
  unsigned short* fmapH   = (unsigned short*)(ws + 12845056);  //  6,553,600
  unsigned short* W1h     = (unsigned short*)(ws + 19398656);  //  4,194,304
  float*          fwh     = (float*)(ws + 23592960);           //  6,553,600
  float*          fwd     = (float*)(ws + 30146560);           //    327,680
  float*          partial = (float*)(ws + 30474240);           //     65,536
  float*          coef    = (float*)(ws + 30539776);           //    501,760

  hipLaunchKernelGGL(k_tc, dim3(5632), dim3(32, 8), 0, stream, img, fmap, fmapH, W1, W1h);
  hipLaunchKernelGGL(k_fwdweff, dim3(144), dim3(256), 0, stream,
                     word, W2, fwd, Wa, W3, partial);
  hipLaunchKernelGGL(k_gemm, dim3(25, 16), dim3(256), 0, stream, fmapH, W1h, fwh);
  hipLaunchKernelGGL(k_coef, dim3(98, 5), dim3(256), 0, stream, fwh, fwd, partial, coef);
  hipLaunchKernelGGL(k_pool, dim3(8, 5, 8), dim3(256), 0, stream, coef, fmap, out);
  (void)in_sizes; (void)n_in; (void)out_size; (void)ws_size;
}